// Round 4
// baseline (280.505 us; speedup 1.0000x reference)
//
#include <hip/hip_runtime.h>

// NCC loss, fused single-pass. Round 4: wave-autonomous vertical-first.
//  - 1 wave = 1 band of BH=4 output rows, full 512-col width: 8 cols/lane.
//  - Vertical running sums over the 9-row window for 16 cols/lane
//    (8 own + 4 halo each side) -> horizontal 9-sum entirely in registers.
//    NO LDS exchange, NO per-row barrier (R3's killer).
//  - Per output row: add-row + sub-row vertical updates (4 predicated
//    float4 loads per input per row), one rolling horizontal pass, cc.
//  - 4096 waves (16/CU target), block = 4 waves, barrier only at the end.
// R3 post-mortem: VALU-busy only 7.3us but per-row __syncthreads + 2-wave
// blocks made it latency-bound (57us, occupancy 10%).

#define W 512
#define H 512
#define BH 4
#define NBANDS (H / BH)      // 128
#define NT 256               // 4 waves per block
#define WPB 4                // waves per block

__device__ __forceinline__ float4 ld4(const float* p) {
    return *reinterpret_cast<const float4*>(p);
}

__global__ __launch_bounds__(NT, 3)
void ncc_main(const float* __restrict__ I, const float* __restrict__ J,
              float* __restrict__ partials) {
    const int lane = threadIdx.x & 63;
    const int wid  = threadIdx.x >> 6;
    const int g    = blockIdx.x * WPB + wid;     // global wave id
    const int b    = g >> 7;                     // g / NBANDS
    const int band = g & (NBANDS - 1);
    const int y0   = band * BH;
    const float* Ip = I + (size_t)b * (H * W);
    const float* Jp = J + (size_t)b * (H * W);
    const int x0 = lane * 8;                     // own cols x0..x0+7

    // Vertical running sums for cols x0-4 .. x0+11 (16), 5 quantities.
    float v[5][16];
    #pragma unroll
    for (int q = 0; q < 5; ++q)
        #pragma unroll
        for (int k = 0; k < 16; ++k) v[q][k] = 0.f;

    const float4 zz = make_float4(0.f, 0.f, 0.f, 0.f);

    auto loadrow = [&](int row, float a[16], float bb[16]) {
        const float* ip = Ip + row * W;
        const float* jp = Jp + row * W;
        float4 A0 = (lane > 0)  ? ld4(ip + x0 - 4) : zz;
        float4 A1 =               ld4(ip + x0);
        float4 A2 =               ld4(ip + x0 + 4);
        float4 A3 = (lane < 63) ? ld4(ip + x0 + 8) : zz;
        float4 B0 = (lane > 0)  ? ld4(jp + x0 - 4) : zz;
        float4 B1 =               ld4(jp + x0);
        float4 B2 =               ld4(jp + x0 + 4);
        float4 B3 = (lane < 63) ? ld4(jp + x0 + 8) : zz;
        a[0]=A0.x; a[1]=A0.y; a[2]=A0.z; a[3]=A0.w;
        a[4]=A1.x; a[5]=A1.y; a[6]=A1.z; a[7]=A1.w;
        a[8]=A2.x; a[9]=A2.y; a[10]=A2.z; a[11]=A2.w;
        a[12]=A3.x; a[13]=A3.y; a[14]=A3.z; a[15]=A3.w;
        bb[0]=B0.x; bb[1]=B0.y; bb[2]=B0.z; bb[3]=B0.w;
        bb[4]=B1.x; bb[5]=B1.y; bb[6]=B1.z; bb[7]=B1.w;
        bb[8]=B2.x; bb[9]=B2.y; bb[10]=B2.z; bb[11]=B2.w;
        bb[12]=B3.x; bb[13]=B3.y; bb[14]=B3.z; bb[15]=B3.w;
    };

    auto vadd = [&](int row) {
        float a[16], bb[16];
        loadrow(row, a, bb);
        #pragma unroll
        for (int k = 0; k < 16; ++k) {
            v[0][k] += a[k];
            v[1][k] += bb[k];
            v[2][k] += a[k] * a[k];
            v[3][k] += bb[k] * bb[k];
            v[4][k] += a[k] * bb[k];
        }
    };
    auto vsub = [&](int row) {
        float a[16], bb[16];
        loadrow(row, a, bb);
        #pragma unroll
        for (int k = 0; k < 16; ++k) {
            v[0][k] -= a[k];
            v[1][k] -= bb[k];
            v[2][k] -= a[k] * a[k];
            v[3][k] -= bb[k] * bb[k];
            v[4][k] -= a[k] * bb[k];
        }
    };

    // Prime with rows y0-4 .. y0+3 (zero pad below row 0).
    #pragma unroll
    for (int dr = -4; dr < 4; ++dr) {
        int r = y0 + dr;
        if (r >= 0) vadd(r);
    }

    float cc_acc = 0.f;
    const float inv81 = 1.f / 81.f;
    #pragma unroll
    for (int i = 0; i < BH; ++i) {
        const int y = y0 + i;
        if (y + 4 < H) vadd(y + 4);   // window -> rows [y-4, y+4] clipped

        // Horizontal 9-sums per quantity, registers only.
        float h[5][8];
        #pragma unroll
        for (int q = 0; q < 5; ++q) {
            float s01 = v[q][0] + v[q][1], s23 = v[q][2] + v[q][3];
            float s45 = v[q][4] + v[q][5], s67 = v[q][6] + v[q][7];
            float t = ((s01 + s23) + (s45 + s67)) + v[q][8];
            h[q][0] = t;
            #pragma unroll
            for (int c = 1; c < 8; ++c) {
                t += v[q][c + 8] - v[q][c - 1];
                h[q][c] = t;
            }
        }

        #pragma unroll
        for (int c = 0; c < 8; ++c) {
            float Is = h[0][c], Js = h[1][c];
            float I2 = h[2][c], J2 = h[3][c], IJ = h[4][c];
            float u     = Is * inv81;
            float cross = IJ - u * Js;
            float Ivar  = I2 - u * Is;
            float Jvar  = J2 - (Js * inv81) * Js;
            float r     = __builtin_amdgcn_rcpf(Ivar * Jvar + 1e-6f);
            cc_acc += (cross * cross) * r;
        }

        if (y - 4 >= 0) vsub(y - 4);  // drop row y-4 for next iteration
    }

    // Wave reduce, then one tiny block reduce (only barrier in the kernel).
    #pragma unroll
    for (int off = 32; off > 0; off >>= 1)
        cc_acc += __shfl_down(cc_acc, off, 64);
    __shared__ float wsum[WPB];
    if (lane == 0) wsum[wid] = cc_acc;
    __syncthreads();
    if (threadIdx.x == 0)
        partials[blockIdx.x] = (wsum[0] + wsum[1]) + (wsum[2] + wsum[3]);
}

__global__ __launch_bounds__(256)
void ncc_finish(const float* __restrict__ partials, float* __restrict__ out,
                int n, float inv_total) {
    float v = 0.f;
    for (int i = threadIdx.x; i < n; i += blockDim.x) v += partials[i];
    #pragma unroll
    for (int off = 32; off > 0; off >>= 1)
        v += __shfl_down(v, off, 64);
    __shared__ float wsum[4];
    if ((threadIdx.x & 63) == 0) wsum[threadIdx.x >> 6] = v;
    __syncthreads();
    if (threadIdx.x == 0) {
        float t = (wsum[0] + wsum[1]) + (wsum[2] + wsum[3]);
        out[0] = 1.0f - t * inv_total;
    }
}

extern "C" void kernel_launch(void* const* d_in, const int* in_sizes, int n_in,
                              void* d_out, int out_size, void* d_ws, size_t ws_size,
                              hipStream_t stream) {
    const float* I = (const float*)d_in[0];   // predict
    const float* J = (const float*)d_in[1];   // target
    float* out = (float*)d_out;
    float* partials = (float*)d_ws;           // nblocks floats (4 KB)

    const int n = in_sizes[0];                // B*1*H*W
    const int B = n / (H * W);
    const int nblocks = B * NBANDS / WPB;     // 1024 for B=32

    ncc_main<<<nblocks, NT, 0, stream>>>(I, J, partials);
    ncc_finish<<<1, 256, 0, stream>>>(partials, out, nblocks, 1.0f / (float)n);
}

// Round 5
// 120.048 us; speedup vs baseline: 2.3366x; 2.3366x over previous
//
#include <hip/hip_runtime.h>

// NCC loss, fused single-pass. Round 5: wave-autonomous vertical-first,
// spill-proofed (R4's array-param lambdas put everything in scratch:
// VGPR=84 but 640 MB of scratch traffic).
//  - 1 wave = 1 band of BH=4 rows, full 512-col width: 8 cols/lane.
//  - 5 vertical running sums (I,J,I2,J2,IJ) per own column, 9-row window,
//    add-row + sub-row per output row (2 float4 loads/input/row).
//  - Horizontal 9-sum: +-4-col halo fetched from neighbor LANES via
//    __shfl_up/__shfl_down (8 shuffles/quantity, LDS pipe, no barrier).
//  - All helpers are MACROS on named locals: nothing can decay to a
//    pointer, nothing can land in scratch.
//  - XCD-aware block swizzle: consecutive bands share 8 halo rows ->
//    keep them on the same XCD's L2.

#define W 512
#define H 512
#define BH 4
#define NBANDS (H / BH)      // 128
#define NT 256               // 4 waves per block
#define WPB 4

__device__ __forceinline__ float4 ld4(const float* p) {
    return *reinterpret_cast<const float4*>(p);
}

// Vertical window update: OP is += or -= ; reads row `row` of both inputs.
#define VROW(row, OP)                                                        \
    do {                                                                     \
        const float* _ip = Ip + (row) * W + x0;                              \
        const float* _jp = Jp + (row) * W + x0;                              \
        float4 _A0 = ld4(_ip);                                               \
        float4 _A1 = ld4(_ip + 4);                                           \
        float4 _B0 = ld4(_jp);                                               \
        float4 _B1 = ld4(_jp + 4);                                           \
        float _a0 = _A0.x, _a1 = _A0.y, _a2 = _A0.z, _a3 = _A0.w;            \
        float _a4 = _A1.x, _a5 = _A1.y, _a6 = _A1.z, _a7 = _A1.w;            \
        float _b0 = _B0.x, _b1 = _B0.y, _b2 = _B0.z, _b3 = _B0.w;            \
        float _b4 = _B1.x, _b5 = _B1.y, _b6 = _B1.z, _b7 = _B1.w;            \
        v0[0] OP _a0; v0[1] OP _a1; v0[2] OP _a2; v0[3] OP _a3;              \
        v0[4] OP _a4; v0[5] OP _a5; v0[6] OP _a6; v0[7] OP _a7;              \
        v1[0] OP _b0; v1[1] OP _b1; v1[2] OP _b2; v1[3] OP _b3;              \
        v1[4] OP _b4; v1[5] OP _b5; v1[6] OP _b6; v1[7] OP _b7;              \
        v2[0] OP _a0*_a0; v2[1] OP _a1*_a1; v2[2] OP _a2*_a2; v2[3] OP _a3*_a3; \
        v2[4] OP _a4*_a4; v2[5] OP _a5*_a5; v2[6] OP _a6*_a6; v2[7] OP _a7*_a7; \
        v3[0] OP _b0*_b0; v3[1] OP _b1*_b1; v3[2] OP _b2*_b2; v3[3] OP _b3*_b3; \
        v3[4] OP _b4*_b4; v3[5] OP _b5*_b5; v3[6] OP _b6*_b6; v3[7] OP _b7*_b7; \
        v4[0] OP _a0*_b0; v4[1] OP _a1*_b1; v4[2] OP _a2*_b2; v4[3] OP _a3*_b3; \
        v4[4] OP _a4*_b4; v4[5] OP _a5*_b5; v4[6] OP _a6*_b6; v4[7] OP _a7*_b7; \
    } while (0)

// Horizontal 9-sum of vv[0..7] + lane-halo via shuffles -> h[0..7].
#define HSUM(vv, h)                                                          \
    do {                                                                     \
        float _l4 = __shfl_up(vv[4], 1),  _l5 = __shfl_up(vv[5], 1);         \
        float _l6 = __shfl_up(vv[6], 1),  _l7 = __shfl_up(vv[7], 1);         \
        float _r0 = __shfl_down(vv[0], 1), _r1 = __shfl_down(vv[1], 1);      \
        float _r2 = __shfl_down(vv[2], 1), _r3 = __shfl_down(vv[3], 1);      \
        _l4 = lane ? _l4 : 0.f; _l5 = lane ? _l5 : 0.f;                      \
        _l6 = lane ? _l6 : 0.f; _l7 = lane ? _l7 : 0.f;                      \
        _r0 = lastl ? 0.f : _r0; _r1 = lastl ? 0.f : _r1;                    \
        _r2 = lastl ? 0.f : _r2; _r3 = lastl ? 0.f : _r3;                    \
        float _t = (((_l4 + _l5) + (_l6 + _l7)) +                            \
                    ((vv[0] + vv[1]) + (vv[2] + vv[3]))) + vv[4];            \
        h[0] = _t;                                                           \
        _t += vv[5] - _l4;  h[1] = _t;                                       \
        _t += vv[6] - _l5;  h[2] = _t;                                       \
        _t += vv[7] - _l6;  h[3] = _t;                                       \
        _t += _r0   - _l7;  h[4] = _t;                                       \
        _t += _r1 - vv[0];  h[5] = _t;                                       \
        _t += _r2 - vv[1];  h[6] = _t;                                       \
        _t += _r3 - vv[2];  h[7] = _t;                                       \
    } while (0)

__global__ __launch_bounds__(NT)
void ncc_main(const float* __restrict__ I, const float* __restrict__ J,
              float* __restrict__ partials) {
    const int lane  = threadIdx.x & 63;
    const bool lastl = (lane == 63);
    const int wid   = threadIdx.x >> 6;

    // XCD swizzle: blocks land on XCDs round-robin by blockIdx; remap so
    // each XCD owns a contiguous range of bands (halo rows stay in its L2).
    const int nblk = gridDim.x;            // 1024, divisible by 8
    const int sblk = (blockIdx.x & 7) * (nblk >> 3) + (blockIdx.x >> 3);

    const int g    = sblk * WPB + wid;     // global wave id, 0..4095
    const int b    = g >> 7;               // g / NBANDS
    const int band = g & (NBANDS - 1);
    const int y0   = band * BH;
    const float* Ip = I + (size_t)b * (H * W);
    const float* Jp = J + (size_t)b * (H * W);
    const int x0 = lane * 8;

    float v0[8], v1[8], v2[8], v3[8], v4[8];
    #pragma unroll
    for (int k = 0; k < 8; ++k) { v0[k]=0.f; v1[k]=0.f; v2[k]=0.f; v3[k]=0.f; v4[k]=0.f; }

    // Prime rows y0-4 .. y0+3 (zero pad above row 0; y0+3 < H always).
    #pragma unroll
    for (int dr = -4; dr < 4; ++dr) {
        int r = y0 + dr;
        if (r >= 0) VROW(r, +=);
    }

    float cc_acc = 0.f;
    const float inv81 = 1.f / 81.f;
    #pragma unroll
    for (int i = 0; i < BH; ++i) {
        const int y = y0 + i;
        if (y + 4 < H) VROW(y + 4, +=);   // window -> rows [y-4, y+4] clipped

        float h0[8], h1[8], h2[8], h3[8], h4[8];
        HSUM(v0, h0);
        HSUM(v1, h1);
        HSUM(v2, h2);
        HSUM(v3, h3);
        HSUM(v4, h4);

        #pragma unroll
        for (int c = 0; c < 8; ++c) {
            float Is = h0[c], Js = h1[c];
            float I2 = h2[c], J2 = h3[c], IJ = h4[c];
            float u     = Is * inv81;
            float cross = IJ - u * Js;
            float Ivar  = I2 - u * Is;
            float Jvar  = J2 - (Js * inv81) * Js;
            float r     = __builtin_amdgcn_rcpf(Ivar * Jvar + 1e-6f);
            cc_acc += (cross * cross) * r;
        }

        if (y - 4 >= 0) VROW(y - 4, -=);  // drop row y-4 for next iteration
    }

    // Wave reduce, then one tiny block reduce (only barrier in the kernel).
    #pragma unroll
    for (int off = 32; off > 0; off >>= 1)
        cc_acc += __shfl_down(cc_acc, off, 64);
    __shared__ float wsum[WPB];
    if (lane == 0) wsum[wid] = cc_acc;
    __syncthreads();
    if (threadIdx.x == 0)
        partials[blockIdx.x] = (wsum[0] + wsum[1]) + (wsum[2] + wsum[3]);
}

__global__ __launch_bounds__(256)
void ncc_finish(const float* __restrict__ partials, float* __restrict__ out,
                int n, float inv_total) {
    float v = 0.f;
    for (int i = threadIdx.x; i < n; i += blockDim.x) v += partials[i];
    #pragma unroll
    for (int off = 32; off > 0; off >>= 1)
        v += __shfl_down(v, off, 64);
    __shared__ float wsum[4];
    if ((threadIdx.x & 63) == 0) wsum[threadIdx.x >> 6] = v;
    __syncthreads();
    if (threadIdx.x == 0) {
        float t = (wsum[0] + wsum[1]) + (wsum[2] + wsum[3]);
        out[0] = 1.0f - t * inv_total;
    }
}

extern "C" void kernel_launch(void* const* d_in, const int* in_sizes, int n_in,
                              void* d_out, int out_size, void* d_ws, size_t ws_size,
                              hipStream_t stream) {
    const float* I = (const float*)d_in[0];   // predict
    const float* J = (const float*)d_in[1];   // target
    float* out = (float*)d_out;
    float* partials = (float*)d_ws;           // nblocks floats (4 KB)

    const int n = in_sizes[0];                // B*1*H*W
    const int B = n / (H * W);
    const int nblocks = B * NBANDS / WPB;     // 1024 for B=32

    ncc_main<<<nblocks, NT, 0, stream>>>(I, J, partials);
    ncc_finish<<<1, 256, 0, stream>>>(partials, out, nblocks, 1.0f / (float)n);
}

// Round 6
// 116.806 us; speedup vs baseline: 2.4015x; 1.0278x over previous
//
#include <hip/hip_runtime.h>

// NCC loss, fused single-pass. Round 6: branch-free + explicitly pipelined.
// R5 post-mortem: ~8us/wave (=1 load-round at a time) because every row pass
// sat inside a wave-uniform branch -> no load hoisting, vmcnt(0) per pass,
// VGPR 152 -> 3 waves/SIMD. Fixes:
//  - Every pass: clamped-row load x uniform mask*sign scalar (prime/add/sub
//    and both image edges unified) -> single basic block, no branches.
//  - Explicit ping-pong: load pass k+2 while accumulating pass k (>=8 loads
//    in flight); cc epilogues overlap in-flight loads.
//  - Epilogue split into lo/hi column halves -> fits 128 VGPR cap,
//    __launch_bounds__(256,4) -> 4 waves/SIMD, 16 waves/CU.
//  - 1 wave = band of BH=4 rows x 512 cols (8 cols/lane), halo via shuffles.

#define W 512
#define H 512
#define BH 4
#define NBANDS (H / BH)      // 128
#define NT 256
#define WPB 4

__device__ __forceinline__ float4 ld4(const float* p) {
    return *reinterpret_cast<const float4*>(p);
}

#define DECLBUF(P) float4 P##A0, P##A1, P##B0, P##B1; float P##m

// Load pass: row y0+DRK clamped to [0,H-1]; mask*sign scalar (0 if OOB).
#define PLOAD(P, DRK, SGNK) do {                                             \
    int _r  = y0 + (DRK);                                                    \
    int _rc = _r < 0 ? 0 : (_r > (H - 1) ? (H - 1) : _r);                    \
    const float* _ip = Ip + _rc * W + x0;                                    \
    const float* _jp = Jp + _rc * W + x0;                                    \
    P##A0 = ld4(_ip);     P##A1 = ld4(_ip + 4);                              \
    P##B0 = ld4(_jp);     P##B1 = ld4(_jp + 4);                              \
    P##m  = (_r == _rc) ? (SGNK) : 0.f;                                      \
} while (0)

// Accumulate pass: v += m*a, m*b, m*a*a, m*b*b, m*a*b (sub via m=-1).
#define PACC(P) do {                                                         \
    float _m = P##m;                                                         \
    float _a0=P##A0.x*_m, _a1=P##A0.y*_m, _a2=P##A0.z*_m, _a3=P##A0.w*_m;    \
    float _a4=P##A1.x*_m, _a5=P##A1.y*_m, _a6=P##A1.z*_m, _a7=P##A1.w*_m;    \
    float _b0=P##B0.x*_m, _b1=P##B0.y*_m, _b2=P##B0.z*_m, _b3=P##B0.w*_m;    \
    float _b4=P##B1.x*_m, _b5=P##B1.y*_m, _b6=P##B1.z*_m, _b7=P##B1.w*_m;    \
    v0[0]+=_a0; v0[1]+=_a1; v0[2]+=_a2; v0[3]+=_a3;                          \
    v0[4]+=_a4; v0[5]+=_a5; v0[6]+=_a6; v0[7]+=_a7;                          \
    v1[0]+=_b0; v1[1]+=_b1; v1[2]+=_b2; v1[3]+=_b3;                          \
    v1[4]+=_b4; v1[5]+=_b5; v1[6]+=_b6; v1[7]+=_b7;                          \
    v2[0]+=_a0*P##A0.x; v2[1]+=_a1*P##A0.y; v2[2]+=_a2*P##A0.z; v2[3]+=_a3*P##A0.w; \
    v2[4]+=_a4*P##A1.x; v2[5]+=_a5*P##A1.y; v2[6]+=_a6*P##A1.z; v2[7]+=_a7*P##A1.w; \
    v3[0]+=_b0*P##B0.x; v3[1]+=_b1*P##B0.y; v3[2]+=_b2*P##B0.z; v3[3]+=_b3*P##B0.w; \
    v3[4]+=_b4*P##B1.x; v3[5]+=_b5*P##B1.y; v3[6]+=_b6*P##B1.z; v3[7]+=_b7*P##B1.w; \
    v4[0]+=_a0*P##B0.x; v4[1]+=_a1*P##B0.y; v4[2]+=_a2*P##B0.z; v4[3]+=_a3*P##B0.w; \
    v4[4]+=_a4*P##B1.x; v4[5]+=_a5*P##B1.y; v4[6]+=_a6*P##B1.z; v4[7]+=_a7*P##B1.w; \
} while (0)

// Horizontal 9-sum, lo half (cols 0..3 of this lane); exports l7 for hi.
#define HLO(vv, h, l7out) do {                                               \
    float _l4 = __shfl_up(vv[4], 1), _l5 = __shfl_up(vv[5], 1);              \
    float _l6 = __shfl_up(vv[6], 1), _l7 = __shfl_up(vv[7], 1);              \
    if (lane == 0) { _l4 = 0.f; _l5 = 0.f; _l6 = 0.f; _l7 = 0.f; }           \
    float _t = (((_l4+_l5)+(_l6+_l7)) + ((vv[0]+vv[1])+(vv[2]+vv[3]))) + vv[4]; \
    h[0] = _t;                                                               \
    _t += vv[5] - _l4; h[1] = _t;                                            \
    _t += vv[6] - _l5; h[2] = _t;                                            \
    _t += vv[7] - _l6; h[3] = _t;                                            \
    l7out = _l7;                                                             \
} while (0)

// Horizontal 9-sum, hi half (cols 4..7), chained from h3/l7.
#define HHI(vv, h3in, l7in, h) do {                                          \
    float _r0 = __shfl_down(vv[0], 1), _r1 = __shfl_down(vv[1], 1);          \
    float _r2 = __shfl_down(vv[2], 1), _r3 = __shfl_down(vv[3], 1);          \
    if (lane == 63) { _r0 = 0.f; _r1 = 0.f; _r2 = 0.f; _r3 = 0.f; }          \
    float _t = (h3in) + _r0 - (l7in); h[0] = _t;                             \
    _t += _r1 - vv[0]; h[1] = _t;                                            \
    _t += _r2 - vv[1]; h[2] = _t;                                            \
    _t += _r3 - vv[2]; h[3] = _t;                                            \
} while (0)

#define CC4(h0a, h1a, h2a, h3a, h4a) do {                                    \
    _Pragma("unroll")                                                        \
    for (int _c = 0; _c < 4; ++_c) {                                         \
        float _Is = h0a[_c], _Js = h1a[_c];                                  \
        float _u  = _Is * inv81;                                             \
        float _cr = h4a[_c] - _u * _Js;                                      \
        float _Iv = h2a[_c] - _u * _Is;                                      \
        float _Jv = h3a[_c] - (_Js * inv81) * _Js;                           \
        cc_acc += (_cr * _cr) * __builtin_amdgcn_rcpf(_Iv * _Jv + 1e-6f);    \
    }                                                                        \
} while (0)

// Full epilogue for one output row: lo-half cc then hi-half cc.
#define EPI() do {                                                           \
    float h0[4], h1[4], h2[4], h3[4], h4[4];                                 \
    float s0, s1, s2, s3, s4;                                                \
    HLO(v0, h0, s0); HLO(v1, h1, s1); HLO(v2, h2, s2);                       \
    HLO(v3, h3, s3); HLO(v4, h4, s4);                                        \
    CC4(h0, h1, h2, h3, h4);                                                 \
    float e0 = h0[3], e1 = h1[3], e2 = h2[3], e3 = h3[3], e4 = h4[3];        \
    HHI(v0, e0, s0, h0); HHI(v1, e1, s1, h1); HHI(v2, e2, s2, h2);           \
    HHI(v3, e3, s3, h3); HHI(v4, e4, s4, h4);                                \
    CC4(h0, h1, h2, h3, h4);                                                 \
} while (0)

__global__ __launch_bounds__(NT, 4)
void ncc_main(const float* __restrict__ I, const float* __restrict__ J,
              float* __restrict__ partials) {
    const int lane = threadIdx.x & 63;
    const int wid  = threadIdx.x >> 6;

    // XCD swizzle: contiguous band ranges per XCD (halo rows share L2).
    const int nblk = gridDim.x;            // 1024, divisible by 8
    const int sblk = (blockIdx.x & 7) * (nblk >> 3) + (blockIdx.x >> 3);

    const int g    = sblk * WPB + wid;     // global wave id
    const int b    = g >> 7;               // g / NBANDS
    const int band = g & (NBANDS - 1);
    const int y0   = band * BH;
    const float* Ip = I + (size_t)b * (H * W);
    const float* Jp = J + (size_t)b * (H * W);
    const int x0 = lane * 8;

    float v0[8], v1[8], v2[8], v3[8], v4[8];
    #pragma unroll
    for (int k = 0; k < 8; ++k) { v0[k]=0.f; v1[k]=0.f; v2[k]=0.f; v3[k]=0.f; v4[k]=0.f; }

    float cc_acc = 0.f;
    const float inv81 = 1.f / 81.f;

    DECLBUF(p); DECLBUF(q);

    // 15 passes: prime rows y0-4..y0+3, then add/sub interleaved; the final
    // sub (row y0-1) is never consumed and is dropped. Ping-pong pipeline:
    // pass k+2's loads issue before pass k+1's accumulate.
    PLOAD(p, -4, 1.f);
    PLOAD(q, -3, 1.f);
    PACC(p); PLOAD(p, -2, 1.f);
    PACC(q); PLOAD(q, -1, 1.f);
    PACC(p); PLOAD(p,  0, 1.f);
    PACC(q); PLOAD(q,  1, 1.f);
    PACC(p); PLOAD(p,  2, 1.f);
    PACC(q); PLOAD(q,  3, 1.f);
    PACC(p); PLOAD(p,  4, 1.f);      // add0 load
    PACC(q); PLOAD(q, -4, -1.f);     // sub0 load
    PACC(p); PLOAD(p,  5, 1.f);      // acc add0; add1 load
    EPI();                            // output row y0
    PACC(q); PLOAD(q, -3, -1.f);     // acc sub0; sub1 load
    PACC(p); PLOAD(p,  6, 1.f);      // acc add1; add2 load
    EPI();                            // y0+1
    PACC(q); PLOAD(q, -2, -1.f);     // acc sub1; sub2 load
    PACC(p); PLOAD(p,  7, 1.f);      // acc add2; add3 load
    EPI();                            // y0+2
    PACC(q);                          // acc sub2
    PACC(p);                          // acc add3
    EPI();                            // y0+3

    // Wave reduce, then one tiny block reduce (only barrier in the kernel).
    #pragma unroll
    for (int off = 32; off > 0; off >>= 1)
        cc_acc += __shfl_down(cc_acc, off, 64);
    __shared__ float wsum[WPB];
    if (lane == 0) wsum[wid] = cc_acc;
    __syncthreads();
    if (threadIdx.x == 0)
        partials[blockIdx.x] = (wsum[0] + wsum[1]) + (wsum[2] + wsum[3]);
}

__global__ __launch_bounds__(256)
void ncc_finish(const float* __restrict__ partials, float* __restrict__ out,
                int n, float inv_total) {
    float v = 0.f;
    for (int i = threadIdx.x; i < n; i += blockDim.x) v += partials[i];
    #pragma unroll
    for (int off = 32; off > 0; off >>= 1)
        v += __shfl_down(v, off, 64);
    __shared__ float wsum[4];
    if ((threadIdx.x & 63) == 0) wsum[threadIdx.x >> 6] = v;
    __syncthreads();
    if (threadIdx.x == 0) {
        float t = (wsum[0] + wsum[1]) + (wsum[2] + wsum[3]);
        out[0] = 1.0f - t * inv_total;
    }
}

extern "C" void kernel_launch(void* const* d_in, const int* in_sizes, int n_in,
                              void* d_out, int out_size, void* d_ws, size_t ws_size,
                              hipStream_t stream) {
    const float* I = (const float*)d_in[0];   // predict
    const float* J = (const float*)d_in[1];   // target
    float* out = (float*)d_out;
    float* partials = (float*)d_ws;           // nblocks floats (4 KB)

    const int n = in_sizes[0];                // B*1*H*W
    const int B = n / (H * W);
    const int nblocks = B * NBANDS / WPB;     // 1024 for B=32

    ncc_main<<<nblocks, NT, 0, stream>>>(I, J, partials);
    ncc_finish<<<1, 256, 0, stream>>>(partials, out, nblocks, 1.0f / (float)n);
}

// Round 7
// 105.844 us; speedup vs baseline: 2.6502x; 1.1036x over previous
//
#include <hip/hip_runtime.h>

// NCC loss, fused single-pass. Round 7: load-once register row-ring.
// Diagnosis R2/R5/R6: all stuck ~45us = 16 waves/CU x 15 load-rounds x ~450cy
// -> per-CU load-round serialization; only fix is fewer loads.
//  - 1 wave = band of BH=16 rows x 512 cols (8 cols/lane). 24 rows/band.
//  - 10 rotating raw-row register buffers (static names, straight-line):
//    each row loaded ONCE (96KB/wave, 12 B/px vs R6's 30); the sub-pass 8
//    outputs later reuses the registers. ~2-output load lookahead.
//  - Branch-free: clamped row + 0/1 mask applied at accumulate time
//    (m in {0,1} => m*a * a == masked square; mask-mul redone in PSUB).
//  - 1024 single-wave blocks, no barriers; shuffles for horizontal halo.

#define W 512
#define H 512
#define BH 16
#define NBANDS (H / BH)      // 32
#define NT 64

__device__ __forceinline__ float4 ld4(const float* p) {
    return *reinterpret_cast<const float4*>(p);
}

#define DECLBUF(P) float4 P##A0, P##A1, P##B0, P##B1; float P##m

// Load row y0+DR (clamped) raw into buffer P; mask 0/1. No use of data here
// -> no waitcnt until PADD consumes it.
#define LOADR(P, DR) do {                                                    \
    int _r  = y0 + (DR);                                                     \
    int _rc = _r < 0 ? 0 : (_r > (H - 1) ? (H - 1) : _r);                    \
    const float* _ip = Ip + _rc * W + x0;                                    \
    const float* _jp = Jp + _rc * W + x0;                                    \
    P##A0 = ld4(_ip);  P##A1 = ld4(_ip + 4);                                 \
    P##B0 = ld4(_jp);  P##B1 = ld4(_jp + 4);                                 \
    P##m  = (_r == _rc) ? 1.f : 0.f;                                         \
} while (0)

// v += masked row products. am = m*a; am*a = m*a*a (m in {0,1}).
#define PBODY(P, OP)                                                         \
    do {                                                                     \
        float _m = P##m;                                                     \
        float _a0=P##A0.x*_m, _a1=P##A0.y*_m, _a2=P##A0.z*_m, _a3=P##A0.w*_m;\
        float _a4=P##A1.x*_m, _a5=P##A1.y*_m, _a6=P##A1.z*_m, _a7=P##A1.w*_m;\
        float _b0=P##B0.x*_m, _b1=P##B0.y*_m, _b2=P##B0.z*_m, _b3=P##B0.w*_m;\
        float _b4=P##B1.x*_m, _b5=P##B1.y*_m, _b6=P##B1.z*_m, _b7=P##B1.w*_m;\
        v0[0] OP _a0; v0[1] OP _a1; v0[2] OP _a2; v0[3] OP _a3;              \
        v0[4] OP _a4; v0[5] OP _a5; v0[6] OP _a6; v0[7] OP _a7;              \
        v1[0] OP _b0; v1[1] OP _b1; v1[2] OP _b2; v1[3] OP _b3;              \
        v1[4] OP _b4; v1[5] OP _b5; v1[6] OP _b6; v1[7] OP _b7;              \
        v2[0] OP _a0*P##A0.x; v2[1] OP _a1*P##A0.y; v2[2] OP _a2*P##A0.z; v2[3] OP _a3*P##A0.w; \
        v2[4] OP _a4*P##A1.x; v2[5] OP _a5*P##A1.y; v2[6] OP _a6*P##A1.z; v2[7] OP _a7*P##A1.w; \
        v3[0] OP _b0*P##B0.x; v3[1] OP _b1*P##B0.y; v3[2] OP _b2*P##B0.z; v3[3] OP _b3*P##B0.w; \
        v3[4] OP _b4*P##B1.x; v3[5] OP _b5*P##B1.y; v3[6] OP _b6*P##B1.z; v3[7] OP _b7*P##B1.w; \
        v4[0] OP _a0*P##B0.x; v4[1] OP _a1*P##B0.y; v4[2] OP _a2*P##B0.z; v4[3] OP _a3*P##B0.w; \
        v4[4] OP _a4*P##B1.x; v4[5] OP _a5*P##B1.y; v4[6] OP _a6*P##B1.z; v4[7] OP _a7*P##B1.w; \
    } while (0)

#define PADD(P) PBODY(P, +=)
#define PSUB(P) PBODY(P, -=)

// Horizontal 9-sum, lo half (cols 0..3 of this lane); exports l7 for hi.
#define HLO(vv, h, l7out) do {                                               \
    float _l4 = __shfl_up(vv[4], 1), _l5 = __shfl_up(vv[5], 1);              \
    float _l6 = __shfl_up(vv[6], 1), _l7 = __shfl_up(vv[7], 1);              \
    if (lane == 0) { _l4 = 0.f; _l5 = 0.f; _l6 = 0.f; _l7 = 0.f; }           \
    float _t = (((_l4+_l5)+(_l6+_l7)) + ((vv[0]+vv[1])+(vv[2]+vv[3]))) + vv[4]; \
    h[0] = _t;                                                               \
    _t += vv[5] - _l4; h[1] = _t;                                            \
    _t += vv[6] - _l5; h[2] = _t;                                            \
    _t += vv[7] - _l6; h[3] = _t;                                            \
    l7out = _l7;                                                             \
} while (0)

// Horizontal 9-sum, hi half (cols 4..7), chained from h3/l7.
#define HHI(vv, h3in, l7in, h) do {                                          \
    float _r0 = __shfl_down(vv[0], 1), _r1 = __shfl_down(vv[1], 1);          \
    float _r2 = __shfl_down(vv[2], 1), _r3 = __shfl_down(vv[3], 1);          \
    if (lane == 63) { _r0 = 0.f; _r1 = 0.f; _r2 = 0.f; _r3 = 0.f; }          \
    float _t = (h3in) + _r0 - (l7in); h[0] = _t;                             \
    _t += _r1 - vv[0]; h[1] = _t;                                            \
    _t += _r2 - vv[1]; h[2] = _t;                                            \
    _t += _r3 - vv[2]; h[3] = _t;                                            \
} while (0)

#define CC4(h0a, h1a, h2a, h3a, h4a) do {                                    \
    _Pragma("unroll")                                                        \
    for (int _c = 0; _c < 4; ++_c) {                                         \
        float _Is = h0a[_c], _Js = h1a[_c];                                  \
        float _u  = _Is * inv81;                                             \
        float _cr = h4a[_c] - _u * _Js;                                      \
        float _Iv = h2a[_c] - _u * _Is;                                      \
        float _Jv = h3a[_c] - (_Js * inv81) * _Js;                           \
        cc_acc += (_cr * _cr) * __builtin_amdgcn_rcpf(_Iv * _Jv + 1e-6f);    \
    }                                                                        \
} while (0)

#define EPI() do {                                                           \
    float h0[4], h1[4], h2[4], h3[4], h4[4];                                 \
    float s0, s1, s2, s3, s4;                                                \
    HLO(v0, h0, s0); HLO(v1, h1, s1); HLO(v2, h2, s2);                       \
    HLO(v3, h3, s3); HLO(v4, h4, s4);                                        \
    CC4(h0, h1, h2, h3, h4);                                                 \
    float e0 = h0[3], e1 = h1[3], e2 = h2[3], e3 = h3[3], e4 = h4[3];        \
    HHI(v0, e0, s0, h0); HHI(v1, e1, s1, h1); HHI(v2, e2, s2, h2);           \
    HHI(v3, e3, s3, h3); HHI(v4, e4, s4, h4);                                \
    CC4(h0, h1, h2, h3, h4);                                                 \
} while (0)

// One output row: add new bottom row, epilogue, drop top row (register-
// resident since its load), optionally load a future row into freed slot.
#define STEPL(AB, SB, DR) do { PADD(AB); EPI(); PSUB(SB); LOADR(SB, DR); } while (0)
#define STEPN(AB, SB)     do { PADD(AB); EPI(); PSUB(SB); } while (0)

__global__ __launch_bounds__(NT)
void ncc_main(const float* __restrict__ I, const float* __restrict__ J,
              float* __restrict__ partials) {
    const int lane = threadIdx.x & 63;

    // XCD swizzle: each XCD gets a contiguous band range (halo rows in L2).
    const int nblk = gridDim.x;            // 1024, divisible by 8
    const int g = (blockIdx.x & 7) * (nblk >> 3) + (blockIdx.x >> 3);

    const int b    = g >> 5;               // g / NBANDS
    const int band = g & (NBANDS - 1);
    const int y0   = band * BH;
    const float* Ip = I + (size_t)b * (H * W);
    const float* Jp = J + (size_t)b * (H * W);
    const int x0 = lane * 8;

    float v0[8], v1[8], v2[8], v3[8], v4[8];
    #pragma unroll
    for (int k = 0; k < 8; ++k) { v0[k]=0.f; v1[k]=0.f; v2[k]=0.f; v3[k]=0.f; v4[k]=0.f; }

    float cc_acc = 0.f;
    const float inv81 = 1.f / 81.f;

    DECLBUF(B0); DECLBUF(B1); DECLBUF(B2); DECLBUF(B3); DECLBUF(B4);
    DECLBUF(B5); DECLBUF(B6); DECLBUF(B7); DECLBUF(B8); DECLBUF(B9);

    // Prologue: issue 10 rows' loads back-to-back (rows y0-4 .. y0+5).
    LOADR(B0, -4); LOADR(B1, -3); LOADR(B2, -2); LOADR(B3, -1);
    LOADR(B4,  0); LOADR(B5,  1); LOADR(B6,  2); LOADR(B7,  3);
    LOADR(B8,  4); LOADR(B9,  5);

    // Prime vertical window with rows y0-4 .. y0+3.
    PADD(B0); PADD(B1); PADD(B2); PADD(B3);
    PADD(B4); PADD(B5); PADD(B6); PADD(B7);

    // 16 output rows. Slot of row r (k=r+4): k%10. Sub slot == next load slot.
    STEPL(B8, B0,  6);   // i=0 : +row4  -row-4  load row6
    STEPL(B9, B1,  7);   // i=1
    STEPL(B0, B2,  8);   // i=2
    STEPL(B1, B3,  9);   // i=3
    STEPL(B2, B4, 10);   // i=4
    STEPL(B3, B5, 11);   // i=5
    STEPL(B4, B6, 12);   // i=6
    STEPL(B5, B7, 13);   // i=7
    STEPL(B6, B8, 14);   // i=8
    STEPL(B7, B9, 15);   // i=9
    STEPL(B8, B0, 16);   // i=10
    STEPL(B9, B1, 17);   // i=11
    STEPL(B0, B2, 18);   // i=12
    STEPL(B1, B3, 19);   // i=13
    STEPN(B2, B4);       // i=14
    STEPN(B3, B5);       // i=15

    // Single-wave block: shuffle reduce, lane 0 writes the partial.
    #pragma unroll
    for (int off = 32; off > 0; off >>= 1)
        cc_acc += __shfl_down(cc_acc, off, 64);
    if (lane == 0) partials[blockIdx.x] = cc_acc;
}

__global__ __launch_bounds__(256)
void ncc_finish(const float* __restrict__ partials, float* __restrict__ out,
                int n, float inv_total) {
    float v = 0.f;
    for (int i = threadIdx.x; i < n; i += blockDim.x) v += partials[i];
    #pragma unroll
    for (int off = 32; off > 0; off >>= 1)
        v += __shfl_down(v, off, 64);
    __shared__ float wsum[4];
    if ((threadIdx.x & 63) == 0) wsum[threadIdx.x >> 6] = v;
    __syncthreads();
    if (threadIdx.x == 0) {
        float t = (wsum[0] + wsum[1]) + (wsum[2] + wsum[3]);
        out[0] = 1.0f - t * inv_total;
    }
}

extern "C" void kernel_launch(void* const* d_in, const int* in_sizes, int n_in,
                              void* d_out, int out_size, void* d_ws, size_t ws_size,
                              hipStream_t stream) {
    const float* I = (const float*)d_in[0];   // predict
    const float* J = (const float*)d_in[1];   // target
    float* out = (float*)d_out;
    float* partials = (float*)d_ws;           // nblocks floats (4 KB)

    const int n = in_sizes[0];                // B*1*H*W
    const int B = n / (H * W);
    const int nblocks = B * NBANDS;           // 1024 for B=32

    ncc_main<<<nblocks, NT, 0, stream>>>(I, J, partials);
    ncc_finish<<<1, 256, 0, stream>>>(partials, out, nblocks, 1.0f / (float)n);
}